// Round 1
// baseline (155.203 us; speedup 1.0000x reference)
//
#include <hip/hip_runtime.h>

#define BS 128
#define NV 24

// Stable (by original index) ascending sort of 4 (x,y) pairs by x.
// Counting-rank formulation: all indices static after unroll -> stays in VGPRs.
__device__ __forceinline__ void sort4_by_x(const float* x, const float* y,
                                           float* sx, float* sy) {
    int rk[4];
#pragma unroll
    for (int a = 0; a < 4; a++) {
        int r = 0;
#pragma unroll
        for (int b = 0; b < 4; b++) {
            r += (x[b] < x[a]) || (x[b] == x[a] && b < a);
        }
        rk[a] = r;
    }
#pragma unroll
    for (int r = 0; r < 4; r++) {
        float vx = 0.f, vy = 0.f;
#pragma unroll
        for (int a = 0; a < 4; a++) {
            if (rk[a] == r) { vx = x[a]; vy = y[a]; }
        }
        sx[r] = vx; sy[r] = vy;
    }
}

__global__ __launch_bounds__(BS, 2)
void fpdiou_kernel(const float* __restrict__ pred, const float* __restrict__ tgt,
                   float* __restrict__ partial, int n)
{
    // [vertex][tid] layout: address stride per vertex = BS*4B, BS%32==0
    // -> bank = tid%32 independent of (divergent) vertex index: conflict-free.
    __shared__ float s_vx[NV * BS];
    __shared__ float s_vy[NV * BS];
    __shared__ float s_ang[NV * BS];
    __shared__ float s_red[2];

    const int tid = threadIdx.x;
    const int i = blockIdx.x * BS + tid;
    float loss = 0.f;

    if (i < n) {
        const float* pp = pred + (size_t)i * 5;
        const float* gg = tgt  + (size_t)i * 5;
        const float pw = pp[2], ph = pp[3];
        const float gw = gg[2], gh = gg[3];

        float c1x[4], c1y[4], c2x[4], c2y[4];
        {
            const float DX[4] = {0.5f, -0.5f, -0.5f, 0.5f};
            const float DY[4] = {0.5f,  0.5f, -0.5f, -0.5f};
            float s, c;
            sincosf(pp[4], &s, &c);
            float x = pp[0], y = pp[1];
#pragma unroll
            for (int q = 0; q < 4; q++) {
                float dx = DX[q] * pw, dy = DY[q] * ph;
                c1x[q] = dx * c - dy * s + x;
                c1y[q] = dx * s + dy * c + y;
            }
            sincosf(gg[4], &s, &c);
            x = gg[0]; y = gg[1];
#pragma unroll
            for (int q = 0; q < 4; q++) {
                float dx = DX[q] * gw, dy = DY[q] * gh;
                c2x[q] = dx * c - dy * s + x;
                c2y[q] = dx * s + dy * c + y;
            }
        }

        // ---- gather candidate vertices in reference concatenation order ----
        int k = 0;
        // corners of box1 inside box2
        {
            const float ax = c2x[0], ay = c2y[0];
            const float abx = c2x[1] - ax, aby = c2y[1] - ay;
            const float adx = c2x[3] - ax, ady = c2y[3] - ay;
            const float dab = abx * abx + aby * aby;
            const float dad = adx * adx + ady * ady;
#pragma unroll
            for (int q = 0; q < 4; q++) {
                float amx = c1x[q] - ax, amy = c1y[q] - ay;
                float pab = (abx * amx + aby * amy) / dab;
                float pd  = (adx * amx + ady * amy) / dad;
                const float e = 1e-6f;
                if (pab > -e && pab < 1.f + e && pd > -e && pd < 1.f + e) {
                    s_vx[k * BS + tid] = c1x[q];
                    s_vy[k * BS + tid] = c1y[q];
                    k++;
                }
            }
        }
        // corners of box2 inside box1
        {
            const float ax = c1x[0], ay = c1y[0];
            const float abx = c1x[1] - ax, aby = c1y[1] - ay;
            const float adx = c1x[3] - ax, ady = c1y[3] - ay;
            const float dab = abx * abx + aby * aby;
            const float dad = adx * adx + ady * ady;
#pragma unroll
            for (int q = 0; q < 4; q++) {
                float amx = c2x[q] - ax, amy = c2y[q] - ay;
                float pab = (abx * amx + aby * amy) / dab;
                float pd  = (adx * amx + ady * amy) / dad;
                const float e = 1e-6f;
                if (pab > -e && pab < 1.f + e && pd > -e && pd < 1.f + e) {
                    s_vx[k * BS + tid] = c2x[q];
                    s_vy[k * BS + tid] = c2y[q];
                    k++;
                }
            }
        }
        // all 4x4 edge-pair intersections (i over c1 edges, j over c2 edges)
#pragma unroll
        for (int a = 0; a < 4; a++) {
            const float x1 = c1x[a], y1 = c1y[a];
            const float x2 = c1x[(a + 1) & 3], y2 = c1y[(a + 1) & 3];
            const float ex = x2 - x1, ey = y2 - y1;
#pragma unroll
            for (int b = 0; b < 4; b++) {
                const float x3 = c2x[b], y3 = c2y[b];
                const float x4 = c2x[(b + 1) & 3], y4 = c2y[(b + 1) & 3];
                const float fx = x4 - x3, fy = y4 - y3;
                // num = (y4-y3)*(x2-x1) - (x4-x3)*(y2-y1)
                const float num = fy * ex - fx * ey;
                if (num != 0.f) {
                    const float dx13 = x1 - x3, dy13 = y1 - y3;
                    const float den_t = fx * dy13 - fy * dx13;
                    const float t = den_t / num;
                    const float den_u = ex * dy13 - ey * dx13;
                    const float u = -den_u / num;
                    if (t > 0.f && t < 1.f && u > 0.f && u < 1.f) {
                        const float t2 = den_t / (num + 1e-8f);
                        s_vx[k * BS + tid] = x1 + t2 * ex;
                        s_vy[k * BS + tid] = y1 + t2 * ey;
                        k++;
                    }
                }
            }
        }

        // ---- polygon area: mean -> angles -> stable sort -> shoelace ----
        float area = 0.f;
        if (k > 0) {
            float sx = 0.f, sy = 0.f;
            for (int v = 0; v < k; v++) {
                sx += s_vx[v * BS + tid];
                sy += s_vy[v * BS + tid];
            }
            const float mx = sx / (float)k;
            const float my = sy / (float)k;
            for (int v = 0; v < k; v++) {
                s_ang[v * BS + tid] =
                    atan2f(s_vy[v * BS + tid] - my, s_vx[v * BS + tid] - mx);
            }
            // stable insertion sort ascending by angle (strict '>' shift keeps
            // equal-angle entries in original order, matching jnp stable argsort)
            for (int v = 1; v < k; v++) {
                float a = s_ang[v * BS + tid];
                float x = s_vx[v * BS + tid];
                float y = s_vy[v * BS + tid];
                int j = v - 1;
                while (j >= 0 && s_ang[j * BS + tid] > a) {
                    s_ang[(j + 1) * BS + tid] = s_ang[j * BS + tid];
                    s_vx[(j + 1) * BS + tid] = s_vx[j * BS + tid];
                    s_vy[(j + 1) * BS + tid] = s_vy[j * BS + tid];
                    j--;
                }
                s_ang[(j + 1) * BS + tid] = a;
                s_vx[(j + 1) * BS + tid] = x;
                s_vy[(j + 1) * BS + tid] = y;
            }
            float cr = 0.f;
            for (int v = 0; v < k; v++) {
                int nx = (v + 1 < k) ? v + 1 : 0;
                cr += s_vx[v * BS + tid] * s_vy[nx * BS + tid]
                    - s_vy[v * BS + tid] * s_vx[nx * BS + tid];
            }
            area = fabsf(cr) * 0.5f;
        }

        // ---- IoU + FPDIoU distance term ----
        const float a1 = pw * ph, a2 = gw * gh;
        float iou = area / (a1 + a2 - area);
        iou = fmaxf(iou, 1e-6f);

        float psx[4], psy[4], gsx[4], gsy[4];
        sort4_by_x(c1x, c1y, psx, psy);
        sort4_by_x(c2x, c2y, gsx, gsy);
        const float d0 = gsx[0] - psx[0];
        float d = 2.f * d0 * d0;
#pragma unroll
        for (int q = 1; q < 4; q++) {
            float dxq = psx[q] - gsx[q];
            float dyq = psy[q] - gsy[q];
            d += dxq * dxq + dyq * dyq;
        }
        const float res = d * (1.f / 4194304.f);  // / (4 * 1024^2)

        loss = 1.f - iou + res;
    }

    // ---- block reduction (wave shuffle, then 2 partials via LDS) ----
#pragma unroll
    for (int off = 32; off > 0; off >>= 1)
        loss += __shfl_down(loss, off, 64);
    if ((tid & 63) == 0) s_red[tid >> 6] = loss;
    __syncthreads();
    if (tid == 0) partial[blockIdx.x] = s_red[0] + s_red[1];
}

__global__ void fpdiou_reduce_kernel(const float* __restrict__ partial, int nblk,
                                     float* __restrict__ out, float inv_n)
{
    __shared__ float red[4];
    float s = 0.f;
    for (int i = threadIdx.x; i < nblk; i += blockDim.x)
        s += partial[i];
#pragma unroll
    for (int off = 32; off > 0; off >>= 1)
        s += __shfl_down(s, off, 64);
    if ((threadIdx.x & 63) == 0) red[threadIdx.x >> 6] = s;
    __syncthreads();
    if (threadIdx.x == 0) {
        float t = red[0] + red[1] + red[2] + red[3];
        out[0] = t * inv_n;
    }
}

extern "C" void kernel_launch(void* const* d_in, const int* in_sizes, int n_in,
                              void* d_out, int out_size, void* d_ws, size_t ws_size,
                              hipStream_t stream)
{
    const float* pred = (const float*)d_in[0];
    const float* tgt  = (const float*)d_in[1];
    float* out = (float*)d_out;
    const int n = in_sizes[0] / 5;
    const int nblk = (n + BS - 1) / BS;
    float* partial = (float*)d_ws;  // nblk floats, overwritten fully each call

    fpdiou_kernel<<<nblk, BS, 0, stream>>>(pred, tgt, partial, n);
    fpdiou_reduce_kernel<<<1, 256, 0, stream>>>(partial, nblk, out, 1.f / (float)n);
}

// Round 2
// 152.706 us; speedup vs baseline: 1.0164x; 1.0164x over previous
//
#include <hip/hip_runtime.h>

#define BS 64
#define NVMAX 16   // intersection of two convex quads: <=8 geometric vertices;
                   // 16 gives slack for tolerance-duplicated corners. Pushes are
                   // clamped at NVMAX (beyond-16 configs are measure-zero degenerate).

// Stable (by original index) ascending sort of 4 (x,y) pairs by x.
// Counting-rank formulation: all indices static after unroll -> stays in VGPRs.
__device__ __forceinline__ void sort4_by_x(const float* x, const float* y,
                                           float* sx, float* sy) {
    int rk[4];
#pragma unroll
    for (int a = 0; a < 4; a++) {
        int r = 0;
#pragma unroll
        for (int b = 0; b < 4; b++) {
            r += (x[b] < x[a]) || (x[b] == x[a] && b < a);
        }
        rk[a] = r;
    }
#pragma unroll
    for (int r = 0; r < 4; r++) {
        float vx = 0.f, vy = 0.f;
#pragma unroll
        for (int a = 0; a < 4; a++) {
            if (rk[a] == r) { vx = x[a]; vy = y[a]; }
        }
        sx[r] = vx; sy[r] = vy;
    }
}

// Strictly monotone surrogate for atan2(dy,dx) on (-pi, pi]:
// p = copysign(1 - dx/(|dx|+|dy|), dy)  in [-2, 2].
// Preserves atan2's total order exactly (same sign structure incl. +/-0),
// so sorting by p == sorting by atan2; ties (identical directions) broken
// by slot index in the successor-find, matching jnp's stable argsort.
__device__ __forceinline__ float pseudo_angle(float dx, float dy) {
    float s = fabsf(dx) + fabsf(dy);
    float r = (s == 0.f) ? 0.f : (1.f - dx / s);
    return copysignf(r, dy);
}

__global__ __launch_bounds__(BS, 2)
void fpdiou_kernel(const float* __restrict__ pred, const float* __restrict__ tgt,
                   float* __restrict__ partial, int n)
{
    // [vertex][tid] layout: stride per vertex = BS*4B, BS%32==0 -> bank = tid%32
    // independent of (divergent) vertex index: conflict-free.
    __shared__ float s_vx[NVMAX * BS];
    __shared__ float s_vy[NVMAX * BS];
    __shared__ float s_p [NVMAX * BS];

    const int tid = threadIdx.x;
    const int i = blockIdx.x * BS + tid;
    float loss = 0.f;

    if (i < n) {
        const float* pp = pred + (size_t)i * 5;
        const float* gg = tgt  + (size_t)i * 5;
        const float pw = pp[2], ph = pp[3];
        const float gw = gg[2], gh = gg[3];

        float c1x[4], c1y[4], c2x[4], c2y[4];
        {
            const float DX[4] = {0.5f, -0.5f, -0.5f, 0.5f};
            const float DY[4] = {0.5f,  0.5f, -0.5f, -0.5f};
            float s, c;
            sincosf(pp[4], &s, &c);
            float x = pp[0], y = pp[1];
#pragma unroll
            for (int q = 0; q < 4; q++) {
                float dx = DX[q] * pw, dy = DY[q] * ph;
                c1x[q] = dx * c - dy * s + x;
                c1y[q] = dx * s + dy * c + y;
            }
            sincosf(gg[4], &s, &c);
            x = gg[0]; y = gg[1];
#pragma unroll
            for (int q = 0; q < 4; q++) {
                float dx = DX[q] * gw, dy = DY[q] * gh;
                c2x[q] = dx * c - dy * s + x;
                c2y[q] = dx * s + dy * c + y;
            }
        }

        // ---- gather candidate vertices in reference concatenation order ----
        // Running sums for the mean (avoids re-reading LDS later).
        int k = 0;
        float sx = 0.f, sy = 0.f;
        // corners of box1 inside box2
        {
            const float ax = c2x[0], ay = c2y[0];
            const float abx = c2x[1] - ax, aby = c2y[1] - ay;
            const float adx = c2x[3] - ax, ady = c2y[3] - ay;
            const float dab = abx * abx + aby * aby;
            const float dad = adx * adx + ady * ady;
#pragma unroll
            for (int q = 0; q < 4; q++) {
                float amx = c1x[q] - ax, amy = c1y[q] - ay;
                float pab = (abx * amx + aby * amy) / dab;
                float pd  = (adx * amx + ady * amy) / dad;
                const float e = 1e-6f;
                if (pab > -e && pab < 1.f + e && pd > -e && pd < 1.f + e) {
                    s_vx[k * BS + tid] = c1x[q];
                    s_vy[k * BS + tid] = c1y[q];
                    sx += c1x[q]; sy += c1y[q];
                    k++;
                }
            }
        }
        // corners of box2 inside box1
        {
            const float ax = c1x[0], ay = c1y[0];
            const float abx = c1x[1] - ax, aby = c1y[1] - ay;
            const float adx = c1x[3] - ax, ady = c1y[3] - ay;
            const float dab = abx * abx + aby * aby;
            const float dad = adx * adx + ady * ady;
#pragma unroll
            for (int q = 0; q < 4; q++) {
                float amx = c2x[q] - ax, amy = c2y[q] - ay;
                float pab = (abx * amx + aby * amy) / dab;
                float pd  = (adx * amx + ady * amy) / dad;
                const float e = 1e-6f;
                if (pab > -e && pab < 1.f + e && pd > -e && pd < 1.f + e) {
                    s_vx[k * BS + tid] = c2x[q];
                    s_vy[k * BS + tid] = c2y[q];
                    sx += c2x[q]; sy += c2y[q];
                    k++;
                }
            }
        }
        // all 4x4 edge-pair intersections, branchless mask:
        // t = den_t/num with num==0 gives inf/NaN -> comparisons false -> excluded,
        // exactly like the reference's where(num==0, -1, ...).
#pragma unroll
        for (int a = 0; a < 4; a++) {
            const float x1 = c1x[a], y1 = c1y[a];
            const float ex = c1x[(a + 1) & 3] - x1, ey = c1y[(a + 1) & 3] - y1;
#pragma unroll
            for (int b = 0; b < 4; b++) {
                const float x3 = c2x[b], y3 = c2y[b];
                const float fx = c2x[(b + 1) & 3] - x3, fy = c2y[(b + 1) & 3] - y3;
                const float num = fy * ex - fx * ey;
                const float dx13 = x1 - x3, dy13 = y1 - y3;
                const float den_t = fx * dy13 - fy * dx13;
                const float den_u = ex * dy13 - ey * dx13;
                const float t = den_t / num;
                const float u = -den_u / num;
                if (t > 0.f && t < 1.f && u > 0.f && u < 1.f && k < NVMAX) {
                    const float t2 = den_t / (num + 1e-8f);   // reference quirk
                    const float ix = x1 + t2 * ex, iy = y1 + t2 * ey;
                    s_vx[k * BS + tid] = ix;
                    s_vy[k * BS + tid] = iy;
                    sx += ix; sy += iy;
                    k++;
                }
            }
        }

        // ---- polygon area: successor-find shoelace (no sort, read-only LDS) ----
        // Equivalent to stable-sort-by-angle + consecutive-pair shoelace:
        // each vertex pairs with the lexicographically-next (angle, idx) key;
        // the max key wraps to the global min key.
        float area = 0.f;
        if (k > 0) {
            const float mx = sx / (float)k;
            const float my = sy / (float)k;
            for (int v = 0; v < k; v++) {
                s_p[v * BS + tid] = pseudo_angle(s_vx[v * BS + tid] - mx,
                                                 s_vy[v * BS + tid] - my);
            }
            // global min key (first index wins ties)
            int mj = 0;
            float mp = s_p[tid];
            for (int j = 1; j < k; j++) {
                float pj = s_p[j * BS + tid];
                if (pj < mp) { mp = pj; mj = j; }
            }
            float cr = 0.f;
            for (int v = 0; v < k; v++) {
                const float pv = s_p[v * BS + tid];
                float bp = 3.4e38f;
                int bj = -1;
                for (int j = 0; j < k; j++) {
                    float pj = s_p[j * BS + tid];
                    bool gt = (pj > pv) || ((pj == pv) && (j > v));
                    if (gt && pj < bp) { bp = pj; bj = j; }
                }
                const int sj = (bj >= 0) ? bj : mj;
                cr += s_vx[v * BS + tid] * s_vy[sj * BS + tid]
                    - s_vy[v * BS + tid] * s_vx[sj * BS + tid];
            }
            area = fabsf(cr) * 0.5f;
        }

        // ---- IoU + FPDIoU distance term ----
        const float a1 = pw * ph, a2 = gw * gh;
        float iou = area / (a1 + a2 - area);
        iou = fmaxf(iou, 1e-6f);

        float psx[4], psy[4], gsx[4], gsy[4];
        sort4_by_x(c1x, c1y, psx, psy);
        sort4_by_x(c2x, c2y, gsx, gsy);
        const float d0 = gsx[0] - psx[0];
        float d = 2.f * d0 * d0;
#pragma unroll
        for (int q = 1; q < 4; q++) {
            float dxq = psx[q] - gsx[q];
            float dyq = psy[q] - gsy[q];
            d += dxq * dxq + dyq * dyq;
        }
        const float res = d * (1.f / 4194304.f);  // / (4 * 1024^2)

        loss = 1.f - iou + res;
    }

    // ---- single-wave block reduction ----
#pragma unroll
    for (int off = 32; off > 0; off >>= 1)
        loss += __shfl_down(loss, off, 64);
    if (tid == 0) partial[blockIdx.x] = loss;
}

__global__ __launch_bounds__(1024)
void fpdiou_reduce_kernel(const float* __restrict__ partial, int nblk,
                          float* __restrict__ out, float inv_n)
{
    __shared__ float red[16];
    float s = 0.f;
    for (int i = threadIdx.x; i < nblk; i += blockDim.x)
        s += partial[i];
#pragma unroll
    for (int off = 32; off > 0; off >>= 1)
        s += __shfl_down(s, off, 64);
    if ((threadIdx.x & 63) == 0) red[threadIdx.x >> 6] = s;
    __syncthreads();
    if (threadIdx.x == 0) {
        float t = 0.f;
#pragma unroll
        for (int w = 0; w < 16; w++) t += red[w];
        out[0] = t * inv_n;
    }
}

extern "C" void kernel_launch(void* const* d_in, const int* in_sizes, int n_in,
                              void* d_out, int out_size, void* d_ws, size_t ws_size,
                              hipStream_t stream)
{
    const float* pred = (const float*)d_in[0];
    const float* tgt  = (const float*)d_in[1];
    float* out = (float*)d_out;
    const int n = in_sizes[0] / 5;
    const int nblk = (n + BS - 1) / BS;
    float* partial = (float*)d_ws;  // nblk floats, fully overwritten each call

    fpdiou_kernel<<<nblk, BS, 0, stream>>>(pred, tgt, partial, n);
    fpdiou_reduce_kernel<<<1, 1024, 0, stream>>>(partial, nblk, out, 1.f / (float)n);
}